// Round 1
// baseline (26696.457 us; speedup 1.0000x reference)
//
#include <hip/hip_runtime.h>
#include <cstdint>
#include <cstddef>

namespace {

constexpr int H    = 300;
constexpr int G4   = 1200;   // 4*H
constexpr int B    = 128;
constexpr int T    = 512;
constexpr int NVOC = 2514;

// ---------------------------------------------------------------------------
// Tiled fp32 GEMM:  out[m][n] = sum_k A[row(m)][k] * W[n][k] + b1[n] (+ b2[n])
// AMODE 0: row = m
// AMODE 1: row = tok[(m&127)*512 + (m>>7)]   (embedding gather, m = t*128+b)
// AMODE 2: row = (m&127)*512 + (m>>7)        ([t,b] -> [b,t] permute)
// K fixed at 300. Tile 128x128, BK=8, 8x8 per thread, 256 threads.
// ---------------------------------------------------------------------------
template<int AMODE, bool HASB2>
__global__ __launch_bounds__(256)
void gemm_tn(const float* __restrict__ A, const float* __restrict__ W,
             const float* __restrict__ b1, const float* __restrict__ b2,
             const int* __restrict__ tok, float* __restrict__ out, int N)
{
    constexpr int K = 300;
    __shared__ __align__(16) float as[8][128];
    __shared__ __align__(16) float bs[8][128];

    const int tid = threadIdx.x;
    const int tx = tid & 15, ty = tid >> 4;
    const int m0 = blockIdx.y * 128;
    const int n0 = blockIdx.x * 128;
    const int rl  = tid >> 1;          // row to load (0..127)
    const int kk0 = (tid & 1) * 4;     // 0 or 4

    // A-row pointer for the loader half-threads
    const int m = m0 + rl;
    int arow;
    if (AMODE == 0) {
        arow = m;
    } else {
        const int q = ((m & 127) << 9) + (m >> 7);
        arow = (AMODE == 1) ? tok[q] : q;
    }
    const float* aptr = A + (size_t)arow * K;
    const int nrow = n0 + rl;
    const float* wptr = W + (size_t)nrow * K;
    const bool nvalid = (nrow < N);

    float acc[8][8];
#pragma unroll
    for (int i = 0; i < 8; ++i)
#pragma unroll
        for (int j = 0; j < 8; ++j) acc[i][j] = 0.f;

    for (int k0 = 0; k0 < K; k0 += 8) {
        float4 av = make_float4(0.f, 0.f, 0.f, 0.f);
        float4 bv = make_float4(0.f, 0.f, 0.f, 0.f);
        const bool kv = (k0 + kk0 < K);          // K=300: last iter kk0=4 is OOB
        if (kv)           av = *(const float4*)(aptr + k0 + kk0);
        if (kv && nvalid) bv = *(const float4*)(wptr + k0 + kk0);
        __syncthreads();   // protect previous iteration's fragment reads
        as[kk0+0][rl] = av.x; as[kk0+1][rl] = av.y; as[kk0+2][rl] = av.z; as[kk0+3][rl] = av.w;
        bs[kk0+0][rl] = bv.x; bs[kk0+1][rl] = bv.y; bs[kk0+2][rl] = bv.z; bs[kk0+3][rl] = bv.w;
        __syncthreads();
#pragma unroll
        for (int kk = 0; kk < 8; ++kk) {
            float4 a0 = *(const float4*)&as[kk][ty*8];
            float4 a1 = *(const float4*)&as[kk][ty*8+4];
            float4 c0 = *(const float4*)&bs[kk][tx*8];
            float4 c1 = *(const float4*)&bs[kk][tx*8+4];
            float a[8] = {a0.x,a0.y,a0.z,a0.w,a1.x,a1.y,a1.z,a1.w};
            float b[8] = {c0.x,c0.y,c0.z,c0.w,c1.x,c1.y,c1.z,c1.w};
#pragma unroll
            for (int i = 0; i < 8; ++i)
#pragma unroll
                for (int j = 0; j < 8; ++j)
                    acc[i][j] = fmaf(a[i], b[j], acc[i][j]);
        }
    }

    // epilogue: bias + store (float2: K6 row pitch 2514*4B is only 8B-aligned)
    float bias[8];
#pragma unroll
    for (int j = 0; j < 8; ++j) {
        const int n = n0 + tx*8 + j;
        float v = 0.f;
        if (n < N) { v = b1[n]; if (HASB2) v += b2[n]; }
        bias[j] = v;
    }
#pragma unroll
    for (int i = 0; i < 8; ++i) {
        const int mi = m0 + ty*8 + i;          // M = 65536 exact, no guard
        float* orow = out + (size_t)mi * N + n0 + tx*8;
#pragma unroll
        for (int j = 0; j < 8; j += 2) {
            const int n = n0 + tx*8 + j;
            if (n + 1 < N) {                    // N is even: no scalar tail
                *(float2*)(orow + j) = make_float2(acc[i][j] + bias[j],
                                                   acc[i][j+1] + bias[j+1]);
            } else if (n < N) {
                orow[j] = acc[i][j] + bias[j];
            }
        }
    }
}

// ---------------------------------------------------------------------------
// Persistent LSTM recurrence (one layer), fp32.
// Grid = 240 blocks = 16 batch-groups x 15 hidden-groups, 1 block/CU (LDS-bound)
// -> all co-resident; homemade monotonic grid barrier per timestep.
// Each block owns 8 batch rows x 20 hidden units; Whh slice (80 rows x 300)
// lives in LDS for all 512 steps. Cross-block h traffic uses agent-scope
// atomics (coherent across XCDs, no cache-invalidate storms).
// ---------------------------------------------------------------------------
constexpr int NWG = 240;
constexpr int HGC = 15;    // hidden groups
constexpr int HS  = 20;    // hidden units per group
constexpr int BS  = 8;     // batch rows per group
constexpr int LTH = 192;   // threads (160 compute + 32 helpers)
constexpr int WPITCH = 301; // LDS pitch: stride%32 = 13 -> 2-way (free)

__device__ __forceinline__ float sigm(float x)     { return 1.f / (1.f + __expf(-x)); }
__device__ __forceinline__ float tanhfast(float x) { return 1.f - 2.f / (__expf(2.f*x) + 1.f); }

__global__ __launch_bounds__(LTH)
void lstm_layer_k(const float* __restrict__ xg, const float* __restrict__ Whh,
                  float* __restrict__ h_all, unsigned* __restrict__ bar)
{
    extern __shared__ float smem[];
    float (*w_lds)[WPITCH] = (float(*)[WPITCH])smem;           // [80][301]
    float* h_flat          = smem + 80*WPITCH;                 // [8][300]
    float (*g_lds)[80]     = (float(*)[80])(smem + 80*WPITCH + BS*H); // [8][80]

    const int tid = threadIdx.x;
    const int bg  = blockIdx.x / HGC;   // 0..15
    const int hg  = blockIdx.x % HGC;   // 0..14

    // stage Whh slice once: rows {g*300 + hg*20 + l}, g=0..3, l=0..19
    for (int idx = tid; idx < 80*75; idx += LTH) {
        const int jl = idx / 75, k4 = (idx % 75) * 4;
        const int jrow = (jl / HS) * H + hg * HS + (jl % HS);
        float4 v = *(const float4*)(Whh + (size_t)jrow * H + k4);
        w_lds[jl][k4+0] = v.x; w_lds[jl][k4+1] = v.y;
        w_lds[jl][k4+2] = v.z; w_lds[jl][k4+3] = v.w;
    }

    const int gj  = tid % 80;        // gate column (g*20+l), compute threads
    const int gbb = (tid % 160) / 80; // 0 or 1: handles b = gbb+{0,2,4,6}
    const int ub  = (tid < 160) ? tid / HS : 0;  // update mapping (b)
    const int ul  = tid % HS;                    // update mapping (l)
    float c = 0.f;                   // private cell state for (ub, ul)

    __syncthreads();

    for (int t = 0; t < T; ++t) {
        // ---- stage h_{t-1} for our 8 batch rows (coherent loads) ----
        if (t == 0) {
            for (int idx = tid; idx < BS*H; idx += LTH) h_flat[idx] = 0.f;
        } else {
            for (int idx = tid; idx < BS*H; idx += LTH) {
                const int bl = idx / H, k = idx % H;
                const float* p = h_all + ((size_t)(bg*BS + bl) * T + (t-1)) * H + k;
                h_flat[idx] = __hip_atomic_load(p, __ATOMIC_RELAXED,
                                                __HIP_MEMORY_SCOPE_AGENT);
            }
        }
        __syncthreads();

        // ---- gates: 4 batch rows per thread share one weight read ----
        if (tid < 160) {
            const int g = gj / HS;
            const int jglob = g * H + hg * HS + (gj % HS);
            const float* xbase = xg + ((size_t)t * B + bg*BS + gbb) * G4 + jglob;
            float a0 = xbase[0*G4], a1 = xbase[2*G4], a2 = xbase[4*G4], a3 = xbase[6*G4];
            const float* wp  = &w_lds[gj][0];
            const float* hp0 = &h_flat[(gbb+0)*H];
            const float* hp2 = &h_flat[(gbb+2)*H];
            const float* hp4 = &h_flat[(gbb+4)*H];
            const float* hp6 = &h_flat[(gbb+6)*H];
#pragma unroll 4
            for (int k = 0; k < H; ++k) {
                const float w = wp[k];
                a0 = fmaf(hp0[k], w, a0);
                a1 = fmaf(hp2[k], w, a1);
                a2 = fmaf(hp4[k], w, a2);
                a3 = fmaf(hp6[k], w, a3);
            }
            if (g == 2) { a0 = tanhfast(a0); a1 = tanhfast(a1); a2 = tanhfast(a2); a3 = tanhfast(a3); }
            else        { a0 = sigm(a0);     a1 = sigm(a1);     a2 = sigm(a2);     a3 = sigm(a3);     }
            g_lds[gbb+0][gj] = a0; g_lds[gbb+2][gj] = a1;
            g_lds[gbb+4][gj] = a2; g_lds[gbb+6][gj] = a3;
        }
        __syncthreads();

        // ---- cell/hidden update: one (b,l) per thread, c in registers ----
        if (tid < 160) {
            const float iG = g_lds[ub][0*HS + ul];
            const float fG = g_lds[ub][1*HS + ul];
            const float gG = g_lds[ub][2*HS + ul];
            const float oG = g_lds[ub][3*HS + ul];
            c = fmaf(fG, c, iG * gG);
            const float hv = oG * tanhfast(c);
            float* p = h_all + ((size_t)(bg*BS + ub) * T + t) * H + hg*HS + ul;
            __hip_atomic_store(p, hv, __ATOMIC_RELAXED, __HIP_MEMORY_SCOPE_AGENT);
        }
        __syncthreads();   // drains vmcnt per wave -> all h stores coherent-complete

        // ---- grid barrier (monotonic counter, all 240 blocks resident) ----
        if (tid == 0) {
            __hip_atomic_fetch_add(bar, 1u, __ATOMIC_RELEASE, __HIP_MEMORY_SCOPE_AGENT);
            const unsigned target = (unsigned)(t + 1) * NWG;
            while (__hip_atomic_load(bar, __ATOMIC_ACQUIRE,
                                     __HIP_MEMORY_SCOPE_AGENT) < target)
                __builtin_amdgcn_s_sleep(2);
        }
        __syncthreads();
    }
}

} // anonymous namespace

// ---------------------------------------------------------------------------
extern "C" void kernel_launch(void* const* d_in, const int* in_sizes, int n_in,
                              void* d_out, int out_size, void* d_ws, size_t ws_size,
                              hipStream_t stream)
{
    const int*   x    = (const int*)  d_in[0];
    const float* emb  = (const float*)d_in[1];
    const float* Wih0 = (const float*)d_in[2];
    const float* Whh0 = (const float*)d_in[3];
    const float* bih0 = (const float*)d_in[4];
    const float* bhh0 = (const float*)d_in[5];
    const float* Wih1 = (const float*)d_in[6];
    const float* Whh1 = (const float*)d_in[7];
    const float* bih1 = (const float*)d_in[8];
    const float* bhh1 = (const float*)d_in[9];
    const float* Wout = (const float*)d_in[10];
    const float* bout = (const float*)d_in[11];

    float* out = (float*)d_out;
    // xg [T][B][4H] fp32 (315 MB) aliases the output buffer (659 MB): it is
    // fully consumed before the final GEMM overwrites d_out.
    float* xg = (float*)d_out;
    float* h1 = (float*)d_ws;                       // [B][T][H] fp32, 78.6 MB
    float* h2 = h1 + (size_t)B * T * H;             // 78.6 MB
    unsigned* bar = (unsigned*)((char*)d_ws + 2 * (size_t)B * T * H * sizeof(float));

    hipMemsetAsync(bar, 0, 2 * sizeof(unsigned), stream);

    constexpr size_t lstm_lds = (size_t)(80*WPITCH + BS*H + BS*80) * sizeof(float); // 108,480 B
    static_assert(lstm_lds < 160*1024, "LDS over budget");
    hipFuncSetAttribute(reinterpret_cast<const void*>(lstm_layer_k),
                        hipFuncAttributeMaxDynamicSharedMemorySize, (int)lstm_lds);

    const dim3 blk(256);
    // L0 input projection, embedding gather fused into A-tile load
    gemm_tn<1, true ><<<dim3(10, 512), blk, 0, stream>>>(emb, Wih0, bih0, bhh0, x, xg, G4);
    // L0 recurrence
    lstm_layer_k<<<dim3(NWG), dim3(LTH), lstm_lds, stream>>>(xg, Whh0, h1, bar);
    // L1 input projection ([b][t] -> [t][b] row permute fused)
    gemm_tn<2, true ><<<dim3(10, 512), blk, 0, stream>>>(h1, Wih1, bih1, bhh1, nullptr, xg, G4);
    // L1 recurrence
    lstm_layer_k<<<dim3(NWG), dim3(LTH), lstm_lds, stream>>>(xg, Whh1, h2, bar + 1);
    // output projection -> logits [b*T+t][NVOC]
    gemm_tn<0, false><<<dim3(20, 512), blk, 0, stream>>>(h2, Wout, bout, nullptr, nullptr, out, NVOC);
}